// Round 4
// baseline (193.096 us; speedup 1.0000x reference)
//
#include <hip/hip_runtime.h>
#include <stdint.h>

#define B_ 2
#define S_ 2048
#define E_ 1024
#define H_ 16
#define D_ 64
#define R_ 16

typedef short s16x8 __attribute__((ext_vector_type(8)));
typedef float f32x4 __attribute__((ext_vector_type(4)));

#define K1_ 0.045084220027780106f   // log2(e)/32
#define K0_ -28.853900817779268f    // -20*log2(e)

// fp32 -> bf16 bits, round-to-nearest (ties away)
__device__ __forceinline__ unsigned short f2bf(float f) {
  union { float f; unsigned u; } v; v.f = f;
  return (unsigned short)((v.u + 0x8000u) >> 16);
}

// async global->LDS, 16B per lane
__device__ __forceinline__ void load_lds16(const void* g, void* l) {
  __builtin_amdgcn_global_load_lds(
      (__attribute__((address_space(1))) void*)(g),
      (__attribute__((address_space(3))) void*)(l), 16, 0, 0);
}

// ---------------- unified prep kernel ----------------
// blocks [0,4096): x fp32->bf16
// blocks [4096,4608): Wq/Wk transpose -> Wt[(which,h,d),e]  (Wq scaled by K1)
// blocks [4608,8704): fused Wv = Wvd@Wvu -> Wt[(2,h,d),e]
// blocks [8704,8716): biases (bq scaled by K1)
__global__ void k_prep(const float* __restrict__ x,
                       const float* __restrict__ Wq, const float* __restrict__ Wk,
                       const float* __restrict__ Wvd, const float* __restrict__ Wvu,
                       const float* __restrict__ bq, const float* __restrict__ bk,
                       const float* __restrict__ bvd, const float* __restrict__ bvu,
                       unsigned short* __restrict__ xb, unsigned short* __restrict__ Wt,
                       float* __restrict__ ball) {
  __shared__ float T[64][65];
  const int blk = blockIdx.x;
  const int t = threadIdx.x;
  if (blk < 4096) {
    int i = (blk * 256 + t) * 4;
    float4 v = *(const float4*)(x + i);
    ushort4 o;
    o.x = f2bf(v.x); o.y = f2bf(v.y); o.z = f2bf(v.z); o.w = f2bf(v.w);
    *(ushort4*)(xb + i) = o;
  } else if (blk < 4608) {
    const int bb = blk - 4096;
    const int which = bb >> 8;
    const int h = (bb >> 4) & 15;
    const int et = bb & 15;
    const float scl = which ? 1.f : K1_;
    const float* src = (which ? Wk : Wq) + (h * E_ + et * 64) * D_;
#pragma unroll
    for (int pr = 0; pr < 4; ++pr) {
      const int row = pr * 16 + (t >> 4);
      const int col = (t & 15) * 4;
      float4 v = *(const float4*)(src + row * 64 + col);
      T[row][col] = v.x; T[row][col + 1] = v.y; T[row][col + 2] = v.z; T[row][col + 3] = v.w;
    }
    __syncthreads();
#pragma unroll
    for (int pr = 0; pr < 4; ++pr) {
      const int d = pr * 16 + (t >> 4);
      const int ec = (t & 15) * 4;
      ushort4 o;
      o.x = f2bf(T[ec][d] * scl); o.y = f2bf(T[ec + 1][d] * scl);
      o.z = f2bf(T[ec + 2][d] * scl); o.w = f2bf(T[ec + 3][d] * scl);
      *(ushort4*)(Wt + ((which << 10) + h * 64 + d) * 1024 + et * 64 + ec) = o;
    }
  } else if (blk < 8704) {
    const int idx = (blk - 4608) * 256 + t;  // 1M
    const int row = idx >> 10;                // h*64+d
    const int e = idx & 1023;
    const int h = row >> 6, d = row & 63;
    const float4* wd4 = (const float4*)(Wvd + (h << 14) + e * 16);
    const float* wu = Wvu + h * R_ * D_ + d;
    float acc = 0.f;
#pragma unroll
    for (int r4 = 0; r4 < 4; ++r4) {
      float4 a = wd4[r4];
      acc += a.x * wu[(r4 * 4 + 0) * 64];
      acc += a.y * wu[(r4 * 4 + 1) * 64];
      acc += a.z * wu[(r4 * 4 + 2) * 64];
      acc += a.w * wu[(r4 * 4 + 3) * 64];
    }
    Wt[(2048 + row) * 1024 + e] = f2bf(acc);
  } else {
    int n = (blk - 8704) * 256 + t;  // 3072
    int which = n >> 10;
    int hd = n & 1023;
    int h = hd >> 6, d = hd & 63;
    float v;
    if (which == 0) v = bq[hd] * K1_;
    else if (which == 1) v = bk[hd];
    else {
      v = bvu[hd];
#pragma unroll
      for (int r = 0; r < R_; ++r) v += bvd[h * R_ + r] * Wvu[(h * R_ + r) * D_ + d];
    }
    ball[n] = v;
  }
}

// ---------------- fused QKV GEMM (proven structure, untouched) ----------------
// cols [0,1024): Q*K1 -> (bh, s, d); [1024,2048): K -> (bh, s, d);
// [2048,3072): V -> transposed (bh, d, s)

__global__ __launch_bounds__(256, 2) void k_gemm_qkv(
    const unsigned short* __restrict__ X, const unsigned short* __restrict__ Wt,
    const float* __restrict__ ball,
    unsigned short* __restrict__ Qb, unsigned short* __restrict__ Kb,
    unsigned short* __restrict__ Vb) {
  __shared__ unsigned short As[128 * 32];
  __shared__ unsigned short Bs[128 * 32];
  const int tid = threadIdx.x;
  const int lane = tid & 63, wave = tid >> 6;
  const int quad = lane >> 4, l16 = lane & 15;
  const int mBase = blockIdx.y * 128, nBase = blockIdx.x * 128;
  const int wm = (wave & 1) * 64, wn = (wave >> 1) * 64;
  const int lrow = lane >> 2, lcol = (lane & 3) * 8;

  f32x4 acc[4][4];
#pragma unroll
  for (int mi = 0; mi < 4; ++mi)
#pragma unroll
    for (int ni = 0; ni < 4; ++ni) acc[mi][ni] = (f32x4){0.f, 0.f, 0.f, 0.f};

  for (int k0 = 0; k0 < E_; k0 += 32) {
#pragma unroll
    for (int i = 0; i < 2; ++i) {
      const int r0 = __builtin_amdgcn_readfirstlane((wave + i * 4) * 16);
      load_lds16(X + (mBase + r0 + lrow) * E_ + k0 + lcol, &As[r0 * 32]);
      load_lds16(Wt + (nBase + r0 + lrow) * E_ + k0 + lcol, &Bs[r0 * 32]);
    }
    __syncthreads();
    s16x8 af[4], bfr[4];
#pragma unroll
    for (int mi = 0; mi < 4; ++mi)
      af[mi] = *(const s16x8*)&As[(wm + mi * 16 + l16) * 32 + quad * 8];
#pragma unroll
    for (int ni = 0; ni < 4; ++ni)
      bfr[ni] = *(const s16x8*)&Bs[(wn + ni * 16 + l16) * 32 + quad * 8];
#pragma unroll
    for (int mi = 0; mi < 4; ++mi)
#pragma unroll
      for (int ni = 0; ni < 4; ++ni)
        acc[mi][ni] = __builtin_amdgcn_mfma_f32_16x16x32_bf16(af[mi], bfr[ni], acc[mi][ni], 0, 0, 0);
    __syncthreads();
  }

  const int which = nBase >> 10;  // uniform per block
#pragma unroll
  for (int ni = 0; ni < 4; ++ni) {
    const int n = nBase + wn + ni * 16 + l16;
    const int nh = n & 1023;
    const int h = nh >> 6, d = nh & 63;
    const float bias = ball[n];
#pragma unroll
    for (int mi = 0; mi < 4; ++mi) {
      const int m0 = mBase + wm + mi * 16 + quad * 4;
      const int b = m0 >> 11;
      const int s = m0 & 2047;
      const int bh = b * H_ + h;
      if (which == 2) {
        ushort4 pk;
        pk.x = f2bf(acc[mi][ni][0] + bias);
        pk.y = f2bf(acc[mi][ni][1] + bias);
        pk.z = f2bf(acc[mi][ni][2] + bias);
        pk.w = f2bf(acc[mi][ni][3] + bias);
        *(ushort4*)(Vb + (bh * D_ + d) * S_ + s) = pk;  // transposed store
      } else {
        unsigned short* dst = (which == 0 ? Qb : Kb) + (bh * S_ + s) * D_ + d;
#pragma unroll
        for (int r = 0; r < 4; ++r) dst[r * D_] = f2bf(acc[mi][ni][r] + bias);
      }
    }
  }
}

// ---------------- flash attention (anti-causal: attend t >= s) ----------------
// R4: R0's PROVEN dataflow (QBLK=64, mfma(Q,K), per-wave Ps LDS P-route,
// elementwise diag mask, per-quad l) + R3's PROVEN free K/V swizzle, with the
// sync structure replaced by a DEPTH-2 COUNTED-VMCNT pipeline (T3+T4):
//   3 LDS buffers; at top of tile kt its DMA was issued TWO tile-computes ago.
//   Each wave waits only its OWN 4 loads (s_waitcnt vmcnt(4): kt's done,
//   kt+1's 4 stay in flight -> never drained in steady state), then raw
//   s_barrier (asm, memory clobber -> no compiler auto-drain). After the
//   barrier all waves' kt rows are visible; DMA for kt+2 targets the buffer
//   of kt-1, whose readers all passed this barrier -> no WAR hazard.
// R3 post-mortem: conflicts -8x and LDS reads -2x changed NOTHING -> kernel is
// latency-bound on the per-tile vmcnt(0) drain, not LDS throughput. This
// round removes the drain and restores TLP (3 blocks/CU, LDS 54272 B).
__global__ __launch_bounds__(256, 3) void k_attn(
    const unsigned short* __restrict__ Qb, const unsigned short* __restrict__ Kb,
    const unsigned short* __restrict__ Vb, float* __restrict__ out) {
  __shared__ unsigned short Ks[3][2 * 64 * 32];   // [buf][dhalf][64 k][32 d] (swizzled)
  __shared__ unsigned short Vs[3][2 * 64 * 32];   // [buf][thalf][64 d][32 t] (swizzled)
  __shared__ unsigned short Ps[4][16][40];        // [wave][q-row][32 t + pad]
  const int tid = threadIdx.x;
  const int lane = tid & 63, wave = tid >> 6;
  const int quad = lane >> 4, l16 = lane & 15;
  const int chunk = blockIdx.x >> 8;
  const int j = blockIdx.x & 255;
  int qt = j >> 3;
  if (chunk & 1) qt = 31 - qt;
  const int bh = (j & 7) + 8 * chunk;
  const int q0 = qt * 64;
  const int r0 = __builtin_amdgcn_readfirstlane(wave * 16);
  const f32x4 kvec = {K0_, K0_, K0_, K0_};

  // DMA source swizzle (per-lane constants; inverse of read-side XOR) [R3-proven]
  const int lrow = lane >> 2;                          // LDS slot row (within 16)
  const int q3w  = ((lrow & 1) << 2) | (lane & 3);     // slot chunk3 within 128B pair
  const int q3e  = q3w ^ ((lrow >> 1) & 7);            // element chunk3 stored here
  const int sr16 = (lrow & ~1) | (q3e >> 2);           // source row (within 16)
  const int sc   = (q3e & 3) * 8;                      // source col (elements)
  // read-side swizzled lane offset within one 512-element (16-row) block
  const int rbase = (l16 >> 1) * 64 + ((((l16 & 1) << 2) | quad) ^ ((l16 >> 1) & 7)) * 8;

  s16x8 qf[2];
  {
    const unsigned short* qp = Qb + (bh * S_ + q0 + wave * 16 + l16) * D_ + quad * 8;
    qf[0] = *(const s16x8*)qp;
    qf[1] = *(const s16x8*)(qp + 32);
  }
  f32x4 o[4];
#pragma unroll
  for (int dc = 0; dc < 4; ++dc) o[dc] = (f32x4){0.f, 0.f, 0.f, 0.f};
  float l_acc[4] = {0.f, 0.f, 0.f, 0.f};

#define DMA_KV(kt_, b_)                                                           \
  {                                                                               \
    _Pragma("unroll")                                                             \
    for (int hdc = 0; hdc < 2; ++hdc) {                                           \
      load_lds16(Kb + (bh * S_ + (kt_) * 64 + r0 + sr16) * D_ + hdc * 32 + sc,    \
                 &Ks[b_][hdc * 2048 + r0 * 32]);                                  \
      load_lds16(Vb + (bh * D_ + r0 + sr16) * S_ + (kt_) * 64 + hdc * 32 + sc,    \
                 &Vs[b_][hdc * 2048 + r0 * 32]);                                  \
    }                                                                             \
  }

  // prologue: prefetch depth 2
  DMA_KV(qt, 0);
  if (qt + 1 < S_ / 64) DMA_KV(qt + 1, 1);

  int cur = 0;  // (kt - qt) % 3
  for (int kt = qt; kt < S_ / 64; ++kt) {
    // wait own 4 loads for tile kt (kt+1's 4 remain in flight); no full drain
    if (kt + 1 < S_ / 64) asm volatile("s_waitcnt vmcnt(4)" ::: "memory");
    else                  asm volatile("s_waitcnt vmcnt(0)" ::: "memory");
    asm volatile("s_barrier" ::: "memory");
    if (kt + 2 < S_ / 64) {
      int b2 = cur + 2; if (b2 >= 3) b2 -= 3;
      DMA_KV(kt + 2, b2);
    }

    const bool diag = (kt == qt);
#pragma unroll
    for (int kc = 0; kc < 2; ++kc) {
      // scores for this 32-t half (tc = kc*2 + tcc), C-init with K0
#pragma unroll
      for (int tcc = 0; tcc < 2; ++tcc) {
        const int tc = kc * 2 + tcc;
        f32x4 a = __builtin_amdgcn_mfma_f32_16x16x32_bf16(
            qf[0], *(const s16x8*)&Ks[cur][tc * 512 + rbase], kvec, 0, 0, 0);
        f32x4 sc4 = __builtin_amdgcn_mfma_f32_16x16x32_bf16(
            qf[1], *(const s16x8*)&Ks[cur][2048 + tc * 512 + rbase], a, 0, 0, 0);
        if (diag) {
#pragma unroll
          for (int r = 0; r < 4; ++r) {
            const int t = tc * 16 + l16;
            const int q = wave * 16 + quad * 4 + r;
            if (t < q) sc4[r] = -200.f;
          }
        }
#pragma unroll
        for (int r = 0; r < 4; ++r) {
          float p = exp2f(sc4[r]);
          l_acc[r] += p;
          Ps[wave][quad * 4 + r][tcc * 16 + l16] =
              (unsigned short)(__float_as_uint(p) >> 16);
        }
      }
      // PV for this half: P A-frag from per-wave LDS (no barrier needed)
      s16x8 pf = *(const s16x8*)&Ps[wave][l16][quad * 8];
#pragma unroll
      for (int dc = 0; dc < 4; ++dc) {
        s16x8 vb = *(const s16x8*)&Vs[cur][kc * 2048 + dc * 512 + rbase];
        o[dc] = __builtin_amdgcn_mfma_f32_16x16x32_bf16(pf, vb, o[dc], 0, 0, 0);
      }
    }
    ++cur; if (cur == 3) cur = 0;
  }
#undef DMA_KV

  // epilogue: reduce l over the 16 lanes holding each row's t-slices
#pragma unroll
  for (int off = 1; off < 16; off <<= 1)
#pragma unroll
    for (int r = 0; r < 4; ++r) l_acc[r] += __shfl_xor(l_acc[r], off);
  float rinv[4];
#pragma unroll
  for (int r = 0; r < 4; ++r) rinv[r] = 1.f / l_acc[r];

  const int b = bh >> 4, h = bh & 15;
#pragma unroll
  for (int dc = 0; dc < 4; ++dc)
#pragma unroll
    for (int r = 0; r < 4; ++r) {
      const int s = q0 + wave * 16 + quad * 4 + r;
      out[(b * S_ + s) * (H_ * D_) + h * D_ + dc * 16 + l16] = o[dc][r] * rinv[r];
    }
}

// ---------------- launch ----------------

extern "C" void kernel_launch(void* const* d_in, const int* in_sizes, int n_in,
                              void* d_out, int out_size, void* d_ws, size_t ws_size,
                              hipStream_t stream) {
  const float* x   = (const float*)d_in[0];
  const float* Wq  = (const float*)d_in[1];
  const float* bq  = (const float*)d_in[2];
  const float* Wk  = (const float*)d_in[3];
  const float* bk  = (const float*)d_in[4];
  const float* Wvd = (const float*)d_in[5];
  const float* bvd = (const float*)d_in[6];
  const float* Wvu = (const float*)d_in[7];
  const float* bvu = (const float*)d_in[8];
  float* out = (float*)d_out;

  char* ws = (char*)d_ws;
  unsigned short* xb   = (unsigned short*)(ws);                    // 8 MB
  unsigned short* Wt   = (unsigned short*)(ws + (8u << 20));       // 6 MB
  float*          ball = (float*)(ws + (14u << 20));               // 12 KB
  unsigned short* Qb   = (unsigned short*)(ws + (15u << 20));      // 8 MB
  unsigned short* Kb   = (unsigned short*)(ws + (23u << 20));      // 8 MB
  unsigned short* Vb   = (unsigned short*)(ws + (31u << 20));      // 8 MB (transposed)

  k_prep<<<8716, 256, 0, stream>>>(x, Wq, Wk, Wvd, Wvu, bq, bk, bvd, bvu, xb, Wt, ball);
  k_gemm_qkv<<<dim3(3072 / 128, 4096 / 128), 256, 0, stream>>>(xb, Wt, ball, Qb, Kb, Vb);
  k_attn<<<1024, 256, 0, stream>>>(Qb, Kb, Vb, out);
}

// Round 5
// 184.185 us; speedup vs baseline: 1.0484x; 1.0484x over previous
//
#include <hip/hip_runtime.h>
#include <stdint.h>

#define B_ 2
#define S_ 2048
#define E_ 1024
#define H_ 16
#define D_ 64
#define R_ 16

typedef short s16x8 __attribute__((ext_vector_type(8)));
typedef float f32x4 __attribute__((ext_vector_type(4)));

#define K1_ 0.045084220027780106f   // log2(e)/32
#define K0_ -28.853900817779268f    // -20*log2(e)

// fp32 -> bf16 bits, round-to-nearest (ties away)
__device__ __forceinline__ unsigned short f2bf(float f) {
  union { float f; unsigned u; } v; v.f = f;
  return (unsigned short)((v.u + 0x8000u) >> 16);
}

// async global->LDS, 16B per lane
__device__ __forceinline__ void load_lds16(const void* g, void* l) {
  __builtin_amdgcn_global_load_lds(
      (__attribute__((address_space(1))) void*)(g),
      (__attribute__((address_space(3))) void*)(l), 16, 0, 0);
}

// ---------------- unified prep kernel (unchanged) ----------------
__global__ void k_prep(const float* __restrict__ x,
                       const float* __restrict__ Wq, const float* __restrict__ Wk,
                       const float* __restrict__ Wvd, const float* __restrict__ Wvu,
                       const float* __restrict__ bq, const float* __restrict__ bk,
                       const float* __restrict__ bvd, const float* __restrict__ bvu,
                       unsigned short* __restrict__ xb, unsigned short* __restrict__ Wt,
                       float* __restrict__ ball) {
  __shared__ float T[64][65];
  const int blk = blockIdx.x;
  const int t = threadIdx.x;
  if (blk < 4096) {
    int i = (blk * 256 + t) * 4;
    float4 v = *(const float4*)(x + i);
    ushort4 o;
    o.x = f2bf(v.x); o.y = f2bf(v.y); o.z = f2bf(v.z); o.w = f2bf(v.w);
    *(ushort4*)(xb + i) = o;
  } else if (blk < 4608) {
    const int bb = blk - 4096;
    const int which = bb >> 8;
    const int h = (bb >> 4) & 15;
    const int et = bb & 15;
    const float scl = which ? 1.f : K1_;
    const float* src = (which ? Wk : Wq) + (h * E_ + et * 64) * D_;
#pragma unroll
    for (int pr = 0; pr < 4; ++pr) {
      const int row = pr * 16 + (t >> 4);
      const int col = (t & 15) * 4;
      float4 v = *(const float4*)(src + row * 64 + col);
      T[row][col] = v.x; T[row][col + 1] = v.y; T[row][col + 2] = v.z; T[row][col + 3] = v.w;
    }
    __syncthreads();
#pragma unroll
    for (int pr = 0; pr < 4; ++pr) {
      const int d = pr * 16 + (t >> 4);
      const int ec = (t & 15) * 4;
      ushort4 o;
      o.x = f2bf(T[ec][d] * scl); o.y = f2bf(T[ec + 1][d] * scl);
      o.z = f2bf(T[ec + 2][d] * scl); o.w = f2bf(T[ec + 3][d] * scl);
      *(ushort4*)(Wt + ((which << 10) + h * 64 + d) * 1024 + et * 64 + ec) = o;
    }
  } else if (blk < 8704) {
    const int idx = (blk - 4608) * 256 + t;  // 1M
    const int row = idx >> 10;                // h*64+d
    const int e = idx & 1023;
    const int h = row >> 6, d = row & 63;
    const float4* wd4 = (const float4*)(Wvd + (h << 14) + e * 16);
    const float* wu = Wvu + h * R_ * D_ + d;
    float acc = 0.f;
#pragma unroll
    for (int r4 = 0; r4 < 4; ++r4) {
      float4 a = wd4[r4];
      acc += a.x * wu[(r4 * 4 + 0) * 64];
      acc += a.y * wu[(r4 * 4 + 1) * 64];
      acc += a.z * wu[(r4 * 4 + 2) * 64];
      acc += a.w * wu[(r4 * 4 + 3) * 64];
    }
    Wt[(2048 + row) * 1024 + e] = f2bf(acc);
  } else {
    int n = (blk - 8704) * 256 + t;  // 3072
    int which = n >> 10;
    int hd = n & 1023;
    int h = hd >> 6, d = hd & 63;
    float v;
    if (which == 0) v = bq[hd] * K1_;
    else if (which == 1) v = bk[hd];
    else {
      v = bvu[hd];
#pragma unroll
      for (int r = 0; r < R_; ++r) v += bvd[h * R_ + r] * Wvu[(h * R_ + r) * D_ + d];
    }
    ball[n] = v;
  }
}

// ---------------- fused QKV GEMM (proven structure, untouched) ----------------
__global__ __launch_bounds__(256, 2) void k_gemm_qkv(
    const unsigned short* __restrict__ X, const unsigned short* __restrict__ Wt,
    const float* __restrict__ ball,
    unsigned short* __restrict__ Qb, unsigned short* __restrict__ Kb,
    unsigned short* __restrict__ Vb) {
  __shared__ unsigned short As[128 * 32];
  __shared__ unsigned short Bs[128 * 32];
  const int tid = threadIdx.x;
  const int lane = tid & 63, wave = tid >> 6;
  const int quad = lane >> 4, l16 = lane & 15;
  const int mBase = blockIdx.y * 128, nBase = blockIdx.x * 128;
  const int wm = (wave & 1) * 64, wn = (wave >> 1) * 64;
  const int lrow = lane >> 2, lcol = (lane & 3) * 8;

  f32x4 acc[4][4];
#pragma unroll
  for (int mi = 0; mi < 4; ++mi)
#pragma unroll
    for (int ni = 0; ni < 4; ++ni) acc[mi][ni] = (f32x4){0.f, 0.f, 0.f, 0.f};

  for (int k0 = 0; k0 < E_; k0 += 32) {
#pragma unroll
    for (int i = 0; i < 2; ++i) {
      const int r0 = __builtin_amdgcn_readfirstlane((wave + i * 4) * 16);
      load_lds16(X + (mBase + r0 + lrow) * E_ + k0 + lcol, &As[r0 * 32]);
      load_lds16(Wt + (nBase + r0 + lrow) * E_ + k0 + lcol, &Bs[r0 * 32]);
    }
    __syncthreads();
    s16x8 af[4], bfr[4];
#pragma unroll
    for (int mi = 0; mi < 4; ++mi)
      af[mi] = *(const s16x8*)&As[(wm + mi * 16 + l16) * 32 + quad * 8];
#pragma unroll
    for (int ni = 0; ni < 4; ++ni)
      bfr[ni] = *(const s16x8*)&Bs[(wn + ni * 16 + l16) * 32 + quad * 8];
#pragma unroll
    for (int mi = 0; mi < 4; ++mi)
#pragma unroll
      for (int ni = 0; ni < 4; ++ni)
        acc[mi][ni] = __builtin_amdgcn_mfma_f32_16x16x32_bf16(af[mi], bfr[ni], acc[mi][ni], 0, 0, 0);
    __syncthreads();
  }

  const int which = nBase >> 10;  // uniform per block
#pragma unroll
  for (int ni = 0; ni < 4; ++ni) {
    const int n = nBase + wn + ni * 16 + l16;
    const int nh = n & 1023;
    const int h = nh >> 6, d = nh & 63;
    const float bias = ball[n];
#pragma unroll
    for (int mi = 0; mi < 4; ++mi) {
      const int m0 = mBase + wm + mi * 16 + quad * 4;
      const int b = m0 >> 11;
      const int s = m0 & 2047;
      const int bh = b * H_ + h;
      if (which == 2) {
        ushort4 pk;
        pk.x = f2bf(acc[mi][ni][0] + bias);
        pk.y = f2bf(acc[mi][ni][1] + bias);
        pk.z = f2bf(acc[mi][ni][2] + bias);
        pk.w = f2bf(acc[mi][ni][3] + bias);
        *(ushort4*)(Vb + (bh * D_ + d) * S_ + s) = pk;  // transposed store
      } else {
        unsigned short* dst = (which == 0 ? Qb : Kb) + (bh * S_ + s) * D_ + d;
#pragma unroll
        for (int r = 0; r < 4; ++r) dst[r * D_] = f2bf(acc[mi][ni][r] + bias);
      }
    }
  }
}

// ---------------- balanced flash attention with exact kt-split partials ----
// Fixed-max softmax => partial (o,l) over any kt-subrange combine by plain
// addition. Per bh: 528 (qt,kt) units split into 32 equal windows (16x17 +
// 16x16). Grid 1024, ALL BLOCKS EQUAL -> 4 blocks/CU for the entire run
// (R0's tail collapsed to 2 blocks/CU on a 33-tile critical path; this is
// 17 tiles at constant 4-deep). Per-tile engine = R0-proven dataflow
// (Ps route, diag mask, drain-0 rhythm) + R3-proven free K/V swizzle.
// A window's qt-segments flush slotted fp32 partials (<=3 contributors per
// (bh,qt), slot = window - first_window(qt)); k_comb sums slots & divides.
// bh = (blk&7)+8*(blk>>8) keeps bh->XCD L2 affinity (4 bh/XCD ~ 2MB).
__global__ __launch_bounds__(256, 4) void k_attn_bal(
    const unsigned short* __restrict__ Qb, const unsigned short* __restrict__ Kb,
    const unsigned short* __restrict__ Vb,
    float* __restrict__ opart, float* __restrict__ lpart) {
  __shared__ unsigned short Ks[2][2 * 64 * 32];   // [buf][dhalf][64 k][32 d] (swizzled)
  __shared__ unsigned short Vs[2][2 * 64 * 32];   // [buf][thalf][64 d][32 t] (swizzled)
  __shared__ unsigned short Ps[4][16][40];        // [wave][q-row][32 t + pad]
  const int tid = threadIdx.x;
  const int lane = tid & 63, wave = tid >> 6;
  const int quad = lane >> 4, l16 = lane & 15;
  const int blk = blockIdx.x;
  const int bh = (blk & 7) + 8 * (blk >> 8);      // XCD affinity
  const int w = (blk & 255) >> 3;                 // window 0..31
  const int lo = (w < 16) ? 17 * w : 272 + 16 * (w - 16);
  const int nsteps = (w < 16) ? 17 : 16;
  const int r0 = __builtin_amdgcn_readfirstlane(wave * 16);
  const f32x4 kvec = {K0_, K0_, K0_, K0_};

  // DMA source swizzle (per-lane constants; inverse of read-side XOR) [R3-proven]
  const int lrow = lane >> 2;
  const int q3w  = ((lrow & 1) << 2) | (lane & 3);
  const int q3e  = q3w ^ ((lrow >> 1) & 7);
  const int sr16 = (lrow & ~1) | (q3e >> 2);
  const int sc   = (q3e & 3) * 8;
  const int rbase = (l16 >> 1) * 64 + ((((l16 & 1) << 2) | quad) ^ ((l16 >> 1) & 7)) * 8;

  // locate first segment of this window
  int qt = 0, uq = 0;  // uq = off(qt), running
  while (uq + (32 - qt) <= lo) { uq += 32 - qt; ++qt; }
  int kt = qt + (lo - uq);

  s16x8 qf0, qf1;
  {
    const unsigned short* qp = Qb + (bh * S_ + qt * 64 + wave * 16 + l16) * D_ + quad * 8;
    qf0 = *(const s16x8*)qp; qf1 = *(const s16x8*)(qp + 32);
  }
  f32x4 o[4];
#pragma unroll
  for (int dc = 0; dc < 4; ++dc) o[dc] = (f32x4){0.f, 0.f, 0.f, 0.f};
  float l_acc[4] = {0.f, 0.f, 0.f, 0.f};

#define DMA_KV_B(kt_, b_)                                                         \
  {                                                                               \
    _Pragma("unroll")                                                             \
    for (int hdc = 0; hdc < 2; ++hdc) {                                           \
      load_lds16(Kb + (bh * S_ + (kt_) * 64 + r0 + sr16) * D_ + hdc * 32 + sc,    \
                 &Ks[b_][hdc * 2048 + r0 * 32]);                                  \
      load_lds16(Vb + (bh * D_ + r0 + sr16) * S_ + (kt_) * 64 + hdc * 32 + sc,    \
                 &Vs[b_][hdc * 2048 + r0 * 32]);                                  \
    }                                                                             \
  }

  DMA_KV_B(kt, 0);  // prologue
  int buf = 0;
  int qt_n = qt, kt_n = kt;  // cursor for next unit

  for (int step = 0; step < nsteps; ++step) {
    __syncthreads();  // drain DMA for buf + prior stores; R0 rhythm
    if (step + 1 < nsteps) {
      if (kt_n < 31) ++kt_n; else { ++qt_n; kt_n = qt_n; }
      DMA_KV_B(kt_n, buf ^ 1);
    }

    const bool diag = (kt == qt);
#pragma unroll
    for (int kc = 0; kc < 2; ++kc) {
#pragma unroll
      for (int tcc = 0; tcc < 2; ++tcc) {
        const int tc = kc * 2 + tcc;
        f32x4 a = __builtin_amdgcn_mfma_f32_16x16x32_bf16(
            qf0, *(const s16x8*)&Ks[buf][tc * 512 + rbase], kvec, 0, 0, 0);
        f32x4 sc4 = __builtin_amdgcn_mfma_f32_16x16x32_bf16(
            qf1, *(const s16x8*)&Ks[buf][2048 + tc * 512 + rbase], a, 0, 0, 0);
        if (diag) {
#pragma unroll
          for (int r = 0; r < 4; ++r) {
            const int t = tc * 16 + l16;
            const int q = wave * 16 + quad * 4 + r;
            if (t < q) sc4[r] = -200.f;
          }
        }
#pragma unroll
        for (int r = 0; r < 4; ++r) {
          float p = exp2f(sc4[r]);
          l_acc[r] += p;
          Ps[wave][quad * 4 + r][tcc * 16 + l16] =
              (unsigned short)(__float_as_uint(p) >> 16);
        }
      }
      s16x8 pf = *(const s16x8*)&Ps[wave][l16][quad * 8];
#pragma unroll
      for (int dc = 0; dc < 4; ++dc) {
        s16x8 vb = *(const s16x8*)&Vs[buf][kc * 2048 + dc * 512 + rbase];
        o[dc] = __builtin_amdgcn_mfma_f32_16x16x32_bf16(pf, vb, o[dc], 0, 0, 0);
      }
    }
    buf ^= 1;

    // ---- segment end: flush slotted partials ----
    const bool segend = (kt == 31) || (step == nsteps - 1);
    if (segend) {
      float lr[4];
#pragma unroll
      for (int r = 0; r < 4; ++r) {
        float v = l_acc[r];
        v += __shfl_xor(v, 1); v += __shfl_xor(v, 2);
        v += __shfl_xor(v, 4); v += __shfl_xor(v, 8);
        lr[r] = v;
      }
      const int sidx = (uq < 272) ? (uq / 17) : 16 + ((uq - 272) >> 4);
      const int slot = w - sidx;
      const int pb = (bh * 32 + qt) * 3 + slot;
      float* op = opart + pb * 4096 + (wave * 16) * 64;
#pragma unroll
      for (int dc = 0; dc < 4; ++dc)
#pragma unroll
        for (int r = 0; r < 4; ++r)
          op[(quad * 4 + r) * 64 + dc * 16 + l16] = o[dc][r];
      if (l16 == 0) {
#pragma unroll
        for (int r = 0; r < 4; ++r)
          lpart[pb * 64 + wave * 16 + quad * 4 + r] = lr[r];
      }
      if (step + 1 < nsteps) {  // set up next segment (qt+1)
        uq += 32 - qt;
        qt = qt_n;
        const unsigned short* qp =
            Qb + (bh * S_ + qt * 64 + wave * 16 + l16) * D_ + quad * 8;
        qf0 = *(const s16x8*)qp; qf1 = *(const s16x8*)(qp + 32);
#pragma unroll
        for (int dc = 0; dc < 4; ++dc) o[dc] = (f32x4){0.f, 0.f, 0.f, 0.f};
#pragma unroll
        for (int r = 0; r < 4; ++r) l_acc[r] = 0.f;
      }
    }
    kt = kt_n;
  }
#undef DMA_KV_B
}

// ---------------- combine partials: out = sum(o) / sum(l) ----------------
__global__ void k_comb(const float* __restrict__ opart, const float* __restrict__ lpart,
                       float* __restrict__ out) {
  const int bh = blockIdx.x >> 5, qt = blockIdx.x & 31;
  const int off = 32 * qt - (qt * (qt - 1)) / 2;
  const int last = off + (32 - qt) - 1;
  const int s0 = (off < 272) ? off / 17 : 16 + (off - 272) / 16;
  const int s1 = (last < 272) ? last / 17 : 16 + (last - 272) / 16;
  const int n = s1 - s0 + 1;
  const int t = threadIdx.x;
  const int row = t >> 2, d0 = (t & 3) * 16;
  const int base = (bh * 32 + qt) * 3;
  float l = 0.f;
  f32x4 acc[4];
#pragma unroll
  for (int j = 0; j < 4; ++j) acc[j] = (f32x4){0.f, 0.f, 0.f, 0.f};
  for (int s = 0; s < n; ++s) {
    l += lpart[(base + s) * 64 + row];
    const f32x4* op = (const f32x4*)(opart + (base + s) * 4096 + row * 64 + d0);
#pragma unroll
    for (int j = 0; j < 4; ++j) acc[j] += op[j];
  }
  const float rinv = 1.f / l;
  const int b = bh >> 4, h = bh & 15;
  float4* dst = (float4*)(out + (b * S_ + qt * 64 + row) * (H_ * D_) + h * D_ + d0);
#pragma unroll
  for (int j = 0; j < 4; ++j) {
    float4 v;
    v.x = acc[j][0] * rinv; v.y = acc[j][1] * rinv;
    v.z = acc[j][2] * rinv; v.w = acc[j][3] * rinv;
    dst[j] = v;
  }
}

// ---------------- R0-exact fallback attention (proven 53 us) ----------------
__global__ __launch_bounds__(256, 4) void k_attn_r0(
    const unsigned short* __restrict__ Qb, const unsigned short* __restrict__ Kb,
    const unsigned short* __restrict__ Vb, float* __restrict__ out) {
  __shared__ unsigned short Ks[2][2 * 64 * 32];
  __shared__ unsigned short Vs[2][2 * 64 * 32];
  __shared__ unsigned short Ps[4][16][40];
  const int tid = threadIdx.x;
  const int lane = tid & 63, wave = tid >> 6;
  const int quad = lane >> 4, l16 = lane & 15;
  const int chunk = blockIdx.x >> 8;
  const int j = blockIdx.x & 255;
  int qt = j >> 3;
  if (chunk & 1) qt = 31 - qt;
  const int bh = (j & 7) + 8 * chunk;
  const int q0 = qt * 64;
  const int lrow = lane >> 2, lcol = (lane & 3) * 8;
  const int r0 = __builtin_amdgcn_readfirstlane(wave * 16);
  const f32x4 kvec = {K0_, K0_, K0_, K0_};

  s16x8 qf[2];
  {
    const unsigned short* qp = Qb + (bh * S_ + q0 + wave * 16 + l16) * D_ + quad * 8;
    qf[0] = *(const s16x8*)qp;
    qf[1] = *(const s16x8*)(qp + 32);
  }
  f32x4 o[4];
#pragma unroll
  for (int dc = 0; dc < 4; ++dc) o[dc] = (f32x4){0.f, 0.f, 0.f, 0.f};
  float l_acc[4] = {0.f, 0.f, 0.f, 0.f};

#define DMA_KV_R(kt_, b_)                                                        \
  {                                                                              \
    _Pragma("unroll")                                                            \
    for (int hdc = 0; hdc < 2; ++hdc) {                                          \
      load_lds16(Kb + (bh * S_ + (kt_) * 64 + r0 + lrow) * D_ + hdc * 32 + lcol, \
                 &Ks[b_][hdc * 2048 + r0 * 32]);                                 \
      load_lds16(Vb + (bh * D_ + r0 + lrow) * S_ + (kt_) * 64 + hdc * 32 + lcol, \
                 &Vs[b_][hdc * 2048 + r0 * 32]);                                 \
    }                                                                            \
  }

  DMA_KV_R(qt, 0);

  int buf = 0;
  for (int kt = qt; kt < S_ / 64; ++kt) {
    __syncthreads();
    if (kt + 1 < S_ / 64) DMA_KV_R(kt + 1, buf ^ 1);

    const bool diag = (kt == qt);
#pragma unroll
    for (int kc = 0; kc < 2; ++kc) {
#pragma unroll
      for (int tcc = 0; tcc < 2; ++tcc) {
        const int tc = kc * 2 + tcc;
        f32x4 a = __builtin_amdgcn_mfma_f32_16x16x32_bf16(
            qf[0], *(const s16x8*)&Ks[buf][(tc * 16 + l16) * 32 + quad * 8], kvec, 0, 0, 0);
        f32x4 sc = __builtin_amdgcn_mfma_f32_16x16x32_bf16(
            qf[1], *(const s16x8*)&Ks[buf][2048 + (tc * 16 + l16) * 32 + quad * 8], a, 0, 0, 0);
        if (diag) {
#pragma unroll
          for (int r = 0; r < 4; ++r) {
            const int t = tc * 16 + l16;
            const int q = wave * 16 + quad * 4 + r;
            if (t < q) sc[r] = -200.f;
          }
        }
#pragma unroll
        for (int r = 0; r < 4; ++r) {
          float p = exp2f(sc[r]);
          l_acc[r] += p;
          Ps[wave][quad * 4 + r][tcc * 16 + l16] =
              (unsigned short)(__float_as_uint(p) >> 16);
        }
      }
      s16x8 pf = *(const s16x8*)&Ps[wave][l16][quad * 8];
#pragma unroll
      for (int dc = 0; dc < 4; ++dc) {
        s16x8 vb = *(const s16x8*)&Vs[buf][kc * 2048 + (dc * 16 + l16) * 32 + quad * 8];
        o[dc] = __builtin_amdgcn_mfma_f32_16x16x32_bf16(pf, vb, o[dc], 0, 0, 0);
      }
    }
    buf ^= 1;
  }
#undef DMA_KV_R

#pragma unroll
  for (int off = 1; off < 16; off <<= 1)
#pragma unroll
    for (int r = 0; r < 4; ++r) l_acc[r] += __shfl_xor(l_acc[r], off);
  float rinv[4];
#pragma unroll
  for (int r = 0; r < 4; ++r) rinv[r] = 1.f / l_acc[r];

  const int b = bh >> 4, h = bh & 15;
#pragma unroll
  for (int dc = 0; dc < 4; ++dc)
#pragma unroll
    for (int r = 0; r < 4; ++r) {
      const int s = q0 + wave * 16 + quad * 4 + r;
      out[(b * S_ + s) * (H_ * D_) + h * D_ + dc * 16 + l16] = o[dc][r] * rinv[r];
    }
}

// ---------------- launch ----------------

extern "C" void kernel_launch(void* const* d_in, const int* in_sizes, int n_in,
                              void* d_out, int out_size, void* d_ws, size_t ws_size,
                              hipStream_t stream) {
  const float* x   = (const float*)d_in[0];
  const float* Wq  = (const float*)d_in[1];
  const float* bq  = (const float*)d_in[2];
  const float* Wk  = (const float*)d_in[3];
  const float* bk  = (const float*)d_in[4];
  const float* Wvd = (const float*)d_in[5];
  const float* bvd = (const float*)d_in[6];
  const float* Wvu = (const float*)d_in[7];
  const float* bvu = (const float*)d_in[8];
  float* out = (float*)d_out;

  char* ws = (char*)d_ws;
  unsigned short* xb   = (unsigned short*)(ws);                    // 8 MB
  unsigned short* Wt   = (unsigned short*)(ws + (8u << 20));       // 6 MB
  float*          ball = (float*)(ws + (14u << 20));               // 12 KB
  unsigned short* Qb   = (unsigned short*)(ws + (15u << 20));      // 8 MB
  unsigned short* Kb   = (unsigned short*)(ws + (23u << 20));      // 8 MB
  unsigned short* Vb   = (unsigned short*)(ws + (31u << 20));      // 8 MB (transposed)

  const size_t OPART_OFF = (size_t)40u << 20;                      // 41,943,040
  const size_t OPART_SZ  = (size_t)32 * 32 * 3 * 4096 * 4;         // 50,331,648
  const size_t LPART_OFF = OPART_OFF + OPART_SZ;
  const size_t LPART_SZ  = (size_t)32 * 32 * 3 * 64 * 4;           // 786,432
  const size_t NEED      = LPART_OFF + LPART_SZ;                   // ~88.8 MiB

  k_prep<<<8716, 256, 0, stream>>>(x, Wq, Wk, Wvd, Wvu, bq, bk, bvd, bvu, xb, Wt, ball);
  k_gemm_qkv<<<dim3(3072 / 128, 4096 / 128), 256, 0, stream>>>(xb, Wt, ball, Qb, Kb, Vb);

  if (ws_size >= NEED) {
    float* opart = (float*)(ws + OPART_OFF);
    float* lpart = (float*)(ws + LPART_OFF);
    k_attn_bal<<<1024, 256, 0, stream>>>(Qb, Kb, Vb, opart, lpart);
    k_comb<<<1024, 256, 0, stream>>>(opart, lpart, out);
  } else {
    k_attn_r0<<<1024, 256, 0, stream>>>(Qb, Kb, Vb, out);
  }
}

// Round 6
// 172.450 us; speedup vs baseline: 1.1197x; 1.0680x over previous
//
#include <hip/hip_runtime.h>
#include <stdint.h>

#define B_ 2
#define S_ 2048
#define E_ 1024
#define H_ 16
#define D_ 64
#define R_ 16

typedef short s16x8 __attribute__((ext_vector_type(8)));
typedef float f32x4 __attribute__((ext_vector_type(4)));

#define K1_ 0.045084220027780106f   // log2(e)/32
#define K0_ -28.853900817779268f    // -20*log2(e)

// fp32 -> bf16 bits, round-to-nearest (ties away)
__device__ __forceinline__ unsigned short f2bf(float f) {
  union { float f; unsigned u; } v; v.f = f;
  return (unsigned short)((v.u + 0x8000u) >> 16);
}

// async global->LDS, 16B per lane
__device__ __forceinline__ void load_lds16(const void* g, void* l) {
  __builtin_amdgcn_global_load_lds(
      (__attribute__((address_space(1))) void*)(g),
      (__attribute__((address_space(3))) void*)(l), 16, 0, 0);
}

// ---------------- unified prep kernel (unchanged) ----------------
// blocks [0,4096): x fp32->bf16
// blocks [4096,4608): Wq/Wk transpose -> Wt[(which,h,d),e]  (Wq scaled by K1)
// blocks [4608,8704): fused Wv = Wvd@Wvu -> Wt[(2,h,d),e]
// blocks [8704,8716): biases (bq scaled by K1)
__global__ void k_prep(const float* __restrict__ x,
                       const float* __restrict__ Wq, const float* __restrict__ Wk,
                       const float* __restrict__ Wvd, const float* __restrict__ Wvu,
                       const float* __restrict__ bq, const float* __restrict__ bk,
                       const float* __restrict__ bvd, const float* __restrict__ bvu,
                       unsigned short* __restrict__ xb, unsigned short* __restrict__ Wt,
                       float* __restrict__ ball) {
  __shared__ float T[64][65];
  const int blk = blockIdx.x;
  const int t = threadIdx.x;
  if (blk < 4096) {
    int i = (blk * 256 + t) * 4;
    float4 v = *(const float4*)(x + i);
    ushort4 o;
    o.x = f2bf(v.x); o.y = f2bf(v.y); o.z = f2bf(v.z); o.w = f2bf(v.w);
    *(ushort4*)(xb + i) = o;
  } else if (blk < 4608) {
    const int bb = blk - 4096;
    const int which = bb >> 8;
    const int h = (bb >> 4) & 15;
    const int et = bb & 15;
    const float scl = which ? 1.f : K1_;
    const float* src = (which ? Wk : Wq) + (h * E_ + et * 64) * D_;
#pragma unroll
    for (int pr = 0; pr < 4; ++pr) {
      const int row = pr * 16 + (t >> 4);
      const int col = (t & 15) * 4;
      float4 v = *(const float4*)(src + row * 64 + col);
      T[row][col] = v.x; T[row][col + 1] = v.y; T[row][col + 2] = v.z; T[row][col + 3] = v.w;
    }
    __syncthreads();
#pragma unroll
    for (int pr = 0; pr < 4; ++pr) {
      const int d = pr * 16 + (t >> 4);
      const int ec = (t & 15) * 4;
      ushort4 o;
      o.x = f2bf(T[ec][d] * scl); o.y = f2bf(T[ec + 1][d] * scl);
      o.z = f2bf(T[ec + 2][d] * scl); o.w = f2bf(T[ec + 3][d] * scl);
      *(ushort4*)(Wt + ((which << 10) + h * 64 + d) * 1024 + et * 64 + ec) = o;
    }
  } else if (blk < 8704) {
    const int idx = (blk - 4608) * 256 + t;  // 1M
    const int row = idx >> 10;                // h*64+d
    const int e = idx & 1023;
    const int h = row >> 6, d = row & 63;
    const float4* wd4 = (const float4*)(Wvd + (h << 14) + e * 16);
    const float* wu = Wvu + h * R_ * D_ + d;
    float acc = 0.f;
#pragma unroll
    for (int r4 = 0; r4 < 4; ++r4) {
      float4 a = wd4[r4];
      acc += a.x * wu[(r4 * 4 + 0) * 64];
      acc += a.y * wu[(r4 * 4 + 1) * 64];
      acc += a.z * wu[(r4 * 4 + 2) * 64];
      acc += a.w * wu[(r4 * 4 + 3) * 64];
    }
    Wt[(2048 + row) * 1024 + e] = f2bf(acc);
  } else {
    int n = (blk - 8704) * 256 + t;  // 3072
    int which = n >> 10;
    int hd = n & 1023;
    int h = hd >> 6, d = hd & 63;
    float v;
    if (which == 0) v = bq[hd] * K1_;
    else if (which == 1) v = bk[hd];
    else {
      v = bvu[hd];
#pragma unroll
      for (int r = 0; r < R_; ++r) v += bvd[h * R_ + r] * Wvu[(h * R_ + r) * D_ + d];
    }
    ball[n] = v;
  }
}

// ---------------- fused QKV GEMM — NOW double-buffered 2-phase (T3 minimum) ----
// R6 change: the old loop was 1-phase single-buffer (STAGE -> full vmcnt(0)
// drain at barrier -> MFMA -> barrier): every K-step exposed the whole L2
// latency. T3-minimum recipe: 2 LDS buffers; issue STAGE for k0+32 BEFORE
// computing k0; ONE __syncthreads per tile. Safety: reads of buf happen
// before the barrier of iter t; overwrites of buf happen after the barrier
// of iter t+1 -> separated by a barrier. The barrier's vmcnt(0) drain now
// lands AFTER the prefetch had the whole compute phase to fly.
// cols [0,1024): Q*K1 -> (bh, s, d); [1024,2048): K -> (bh, s, d);
// [2048,3072): V -> transposed (bh, d, s)
__global__ __launch_bounds__(256, 2) void k_gemm_qkv(
    const unsigned short* __restrict__ X, const unsigned short* __restrict__ Wt,
    const float* __restrict__ ball,
    unsigned short* __restrict__ Qb, unsigned short* __restrict__ Kb,
    unsigned short* __restrict__ Vb) {
  __shared__ unsigned short As[2][128 * 32];
  __shared__ unsigned short Bs[2][128 * 32];
  const int tid = threadIdx.x;
  const int lane = tid & 63, wave = tid >> 6;
  const int quad = lane >> 4, l16 = lane & 15;
  const int mBase = blockIdx.y * 128, nBase = blockIdx.x * 128;
  const int wm = (wave & 1) * 64, wn = (wave >> 1) * 64;
  const int lrow = lane >> 2, lcol = (lane & 3) * 8;

  f32x4 acc[4][4];
#pragma unroll
  for (int mi = 0; mi < 4; ++mi)
#pragma unroll
    for (int ni = 0; ni < 4; ++ni) acc[mi][ni] = (f32x4){0.f, 0.f, 0.f, 0.f};

#define STAGE(b_, k0_)                                                          \
  {                                                                             \
    _Pragma("unroll")                                                           \
    for (int i = 0; i < 2; ++i) {                                               \
      const int r0 = __builtin_amdgcn_readfirstlane((wave + i * 4) * 16);       \
      load_lds16(X + (mBase + r0 + lrow) * E_ + (k0_) + lcol,                   \
                 &As[b_][r0 * 32]);                                             \
      load_lds16(Wt + (nBase + r0 + lrow) * E_ + (k0_) + lcol,                  \
                 &Bs[b_][r0 * 32]);                                             \
    }                                                                           \
  }

  STAGE(0, 0);
  __syncthreads();  // buffer 0 ready
  int buf = 0;
  for (int k0 = 0; k0 < E_; k0 += 32) {
    if (k0 + 32 < E_) STAGE(buf ^ 1, k0 + 32);  // prefetch next tile FIRST
    s16x8 af[4], bfr[4];
#pragma unroll
    for (int mi = 0; mi < 4; ++mi)
      af[mi] = *(const s16x8*)&As[buf][(wm + mi * 16 + l16) * 32 + quad * 8];
#pragma unroll
    for (int ni = 0; ni < 4; ++ni)
      bfr[ni] = *(const s16x8*)&Bs[buf][(wn + ni * 16 + l16) * 32 + quad * 8];
#pragma unroll
    for (int mi = 0; mi < 4; ++mi)
#pragma unroll
      for (int ni = 0; ni < 4; ++ni)
        acc[mi][ni] = __builtin_amdgcn_mfma_f32_16x16x32_bf16(af[mi], bfr[ni], acc[mi][ni], 0, 0, 0);
    __syncthreads();  // prefetch drained + all reads of buf done
    buf ^= 1;
  }
#undef STAGE

  const int which = nBase >> 10;  // uniform per block
#pragma unroll
  for (int ni = 0; ni < 4; ++ni) {
    const int n = nBase + wn + ni * 16 + l16;
    const int nh = n & 1023;
    const int h = nh >> 6, d = nh & 63;
    const float bias = ball[n];
#pragma unroll
    for (int mi = 0; mi < 4; ++mi) {
      const int m0 = mBase + wm + mi * 16 + quad * 4;
      const int b = m0 >> 11;
      const int s = m0 & 2047;
      const int bh = b * H_ + h;
      if (which == 2) {
        ushort4 pk;
        pk.x = f2bf(acc[mi][ni][0] + bias);
        pk.y = f2bf(acc[mi][ni][1] + bias);
        pk.z = f2bf(acc[mi][ni][2] + bias);
        pk.w = f2bf(acc[mi][ni][3] + bias);
        *(ushort4*)(Vb + (bh * D_ + d) * S_ + s) = pk;  // transposed store
      } else {
        unsigned short* dst = (which == 0 ? Qb : Kb) + (bh * S_ + s) * D_ + d;
#pragma unroll
        for (int r = 0; r < 4; ++r) dst[r * D_] = f2bf(acc[mi][ni][r] + bias);
      }
    }
  }
}

// ---------------- flash attention — R0-EXACT revert (proven 53.0 us) --------
// anti-causal: attend t >= s. K AND V double-buffered in LDS via DMA; ONE
// barrier per tile, prefetch for kt+1 issued right after the barrier. Ps is
// a single 32-t half per wave. 1024 blocks, chunk-balanced qt mapping.
// Fixed-max softmax: Q pre-scaled by K1, QK C-initialized with K0.
__global__ __launch_bounds__(256, 4) void k_attn(
    const unsigned short* __restrict__ Qb, const unsigned short* __restrict__ Kb,
    const unsigned short* __restrict__ Vb, float* __restrict__ out) {
  __shared__ unsigned short Ks[2][2 * 64 * 32];   // [buf][dhalf][64 k][32 d]
  __shared__ unsigned short Vs[2][2 * 64 * 32];   // [buf][thalf][64 d][32 t]
  __shared__ unsigned short Ps[4][16][40];        // [wave][q-row][32 t + pad]
  const int tid = threadIdx.x;
  const int lane = tid & 63, wave = tid >> 6;
  const int quad = lane >> 4, l16 = lane & 15;
  const int chunk = blockIdx.x >> 8;
  const int j = blockIdx.x & 255;
  int qt = j >> 3;
  if (chunk & 1) qt = 31 - qt;
  const int bh = (j & 7) + 8 * chunk;
  const int q0 = qt * 64;
  const int lrow = lane >> 2, lcol = (lane & 3) * 8;
  const int r0 = __builtin_amdgcn_readfirstlane(wave * 16);
  const f32x4 kvec = {K0_, K0_, K0_, K0_};

  s16x8 qf[2];
  {
    const unsigned short* qp = Qb + (bh * S_ + q0 + wave * 16 + l16) * D_ + quad * 8;
    qf[0] = *(const s16x8*)qp;
    qf[1] = *(const s16x8*)(qp + 32);
  }
  f32x4 o[4];
#pragma unroll
  for (int dc = 0; dc < 4; ++dc) o[dc] = (f32x4){0.f, 0.f, 0.f, 0.f};
  float l_acc[4] = {0.f, 0.f, 0.f, 0.f};

#define DMA_KV(kt_, b_)                                                          \
  {                                                                              \
    _Pragma("unroll")                                                            \
    for (int hdc = 0; hdc < 2; ++hdc) {                                          \
      load_lds16(Kb + (bh * S_ + (kt_) * 64 + r0 + lrow) * D_ + hdc * 32 + lcol, \
                 &Ks[b_][hdc * 2048 + r0 * 32]);                                 \
      load_lds16(Vb + (bh * D_ + r0 + lrow) * S_ + (kt_) * 64 + hdc * 32 + lcol, \
                 &Vs[b_][hdc * 2048 + r0 * 32]);                                 \
    }                                                                            \
  }

  // prologue: stage tile qt into buffer 0
  DMA_KV(qt, 0);

  int buf = 0;
  for (int kt = qt; kt < S_ / 64; ++kt) {
    __syncthreads();  // Ks/Vs[buf] DMA drained; prior reads of buf^1 done
    if (kt + 1 < S_ / 64) DMA_KV(kt + 1, buf ^ 1);

    const bool diag = (kt == qt);
#pragma unroll
    for (int kc = 0; kc < 2; ++kc) {
      // scores for this 32-t half (tc = kc*2 + tcc), C-init with K0
#pragma unroll
      for (int tcc = 0; tcc < 2; ++tcc) {
        const int tc = kc * 2 + tcc;
        f32x4 a = __builtin_amdgcn_mfma_f32_16x16x32_bf16(
            qf[0], *(const s16x8*)&Ks[buf][(tc * 16 + l16) * 32 + quad * 8], kvec, 0, 0, 0);
        f32x4 sc = __builtin_amdgcn_mfma_f32_16x16x32_bf16(
            qf[1], *(const s16x8*)&Ks[buf][2048 + (tc * 16 + l16) * 32 + quad * 8], a, 0, 0, 0);
        if (diag) {
#pragma unroll
          for (int r = 0; r < 4; ++r) {
            const int t = tc * 16 + l16;
            const int q = wave * 16 + quad * 4 + r;
            if (t < q) sc[r] = -200.f;
          }
        }
#pragma unroll
        for (int r = 0; r < 4; ++r) {
          float p = exp2f(sc[r]);
          l_acc[r] += p;
          Ps[wave][quad * 4 + r][tcc * 16 + l16] =
              (unsigned short)(__float_as_uint(p) >> 16);
        }
      }
      // PV for this half: P A-frag from per-wave LDS (no barrier)
      s16x8 pf = *(const s16x8*)&Ps[wave][l16][quad * 8];
#pragma unroll
      for (int dc = 0; dc < 4; ++dc) {
        s16x8 vb = *(const s16x8*)&Vs[buf][kc * 2048 + (dc * 16 + l16) * 32 + quad * 8];
        o[dc] = __builtin_amdgcn_mfma_f32_16x16x32_bf16(pf, vb, o[dc], 0, 0, 0);
      }
    }
    buf ^= 1;
  }
#undef DMA_KV

  // epilogue: reduce l over the 16 lanes holding each row's t-slices
#pragma unroll
  for (int off = 1; off < 16; off <<= 1)
#pragma unroll
    for (int r = 0; r < 4; ++r) l_acc[r] += __shfl_xor(l_acc[r], off);
  float rinv[4];
#pragma unroll
  for (int r = 0; r < 4; ++r) rinv[r] = 1.f / l_acc[r];

  const int b = bh >> 4, h = bh & 15;
#pragma unroll
  for (int dc = 0; dc < 4; ++dc)
#pragma unroll
    for (int r = 0; r < 4; ++r) {
      const int s = q0 + wave * 16 + quad * 4 + r;
      out[(b * S_ + s) * (H_ * D_) + h * D_ + dc * 16 + l16] = o[dc][r] * rinv[r];
    }
}

// ---------------- launch ----------------

extern "C" void kernel_launch(void* const* d_in, const int* in_sizes, int n_in,
                              void* d_out, int out_size, void* d_ws, size_t ws_size,
                              hipStream_t stream) {
  const float* x   = (const float*)d_in[0];
  const float* Wq  = (const float*)d_in[1];
  const float* bq  = (const float*)d_in[2];
  const float* Wk  = (const float*)d_in[3];
  const float* bk  = (const float*)d_in[4];
  const float* Wvd = (const float*)d_in[5];
  const float* bvd = (const float*)d_in[6];
  const float* Wvu = (const float*)d_in[7];
  const float* bvu = (const float*)d_in[8];
  float* out = (float*)d_out;

  char* ws = (char*)d_ws;
  unsigned short* xb   = (unsigned short*)(ws);                    // 8 MB
  unsigned short* Wt   = (unsigned short*)(ws + (8u << 20));       // 6 MB
  float*          ball = (float*)(ws + (14u << 20));               // 12 KB
  unsigned short* Qb   = (unsigned short*)(ws + (15u << 20));      // 8 MB
  unsigned short* Kb   = (unsigned short*)(ws + (23u << 20));      // 8 MB
  unsigned short* Vb   = (unsigned short*)(ws + (31u << 20));      // 8 MB (transposed)

  k_prep<<<8716, 256, 0, stream>>>(x, Wq, Wk, Wvd, Wvu, bq, bk, bvd, bvu, xb, Wt, ball);
  k_gemm_qkv<<<dim3(3072 / 128, 4096 / 128), 256, 0, stream>>>(xb, Wt, ball, Qb, Kb, Vb);
  k_attn<<<1024, 256, 0, stream>>>(Qb, Kb, Vb, out);
}